// Round 3
// baseline (392.643 us; speedup 1.0000x reference)
//
#include <hip/hip_runtime.h>

// Problem constants (fixed by the reference)
#define T_TOKENS 16384   // B*S = 4*4096
#define HDIM     2048
#define NEXP     8
#define TPW      2                               // tokens per wave
#define WPB      4                               // waves per block (256 threads)
#define TOK_PER_BLOCK (WPB * TPW)                // 8
#define NBLOCKS  (T_TOKENS / TOK_PER_BLOCK)      // 2048

__device__ __forceinline__ float dot4(float4 a, float4 b) {
    return a.x * b.x + a.y * b.y + a.z * b.z + a.w * b.w;
}

// Value-splitting butterfly stage: 2*D live accumulators -> D.
// Takes the array by reference (not pointer) so SROA keeps it in registers.
template <int D>
__device__ __forceinline__ void reduce_stage(float (&acc)[TPW * NEXP], int lane) {
    const bool upper = (lane & D) != 0;
#pragma unroll
    for (int i = 0; i < D; ++i) {
        float send = upper ? acc[i] : acc[i + D];
        float recv = __shfl_xor(send, D, 64);
        float keep = upper ? acc[i + D] : acc[i];
        acc[i] = keep + recv;
    }
}

// __launch_bounds__(256, 6): VGPR cap ~84 vs ~56 live set -> headroom, NO SPILL.
// (Round-2 lesson: the (1024,8) 64-VGPR cap made the allocator spill acc[] to
// scratch -> 159 MB/dispatch of scratch write-back, 7.5% VALUBusy, 133 us.)
// No LDS gate: gate_w (64 KB) is L2-resident per XCD; this frees block size
// from the 64 KB LDS constraint and removes the staging barrier entirely.
__global__ __launch_bounds__(256, 6) void router_fused(
    const float* __restrict__ x, const float* __restrict__ gate_w,
    float* __restrict__ out, int* __restrict__ gcnt, int* __restrict__ flag) {
    __shared__ int hist[NEXP];

    const int tid = threadIdx.x;
    if (tid < NEXP) hist[tid] = 0;
    __syncthreads();

    const int lane   = tid & 63;
    const int wave   = tid >> 6;
    const int t_base = (blockIdx.x * WPB + wave) * TPW;  // exact cover of T_TOKENS

    float acc[TPW * NEXP];  // acc[t*8+e] — 16 VGPRs
#pragma unroll
    for (int v = 0; v < TPW * NEXP; ++v) acc[v] = 0.f;

    const float4* x4 = (const float4*)x;
    const float4* g4 = (const float4*)gate_w;
    const int     row = HDIM / 4;  // 512 float4 per token / per expert row

    // Chunk = 256 floats of H (64 lanes x float4); 8 chunks cover H=2048.
    // Prefetch chunk c+1's x while computing chunk c. Gate reads come from
    // L2 (64 KB, hot in every XCD after the first blocks touch it).
    float4 xv[TPW], xn[TPW];
#pragma unroll
    for (int t = 0; t < TPW; ++t)
        xv[t] = x4[(size_t)(t_base + t) * row + lane];

#pragma unroll 2
    for (int c = 0; c < HDIM / 256; ++c) {
        if (c + 1 < HDIM / 256) {
#pragma unroll
            for (int t = 0; t < TPW; ++t)
                xn[t] = x4[(size_t)(t_base + t) * row + (c + 1) * 64 + lane];
        }
#pragma unroll
        for (int e = 0; e < NEXP; ++e) {
            float4 gv = g4[e * row + c * 64 + lane];
#pragma unroll
            for (int t = 0; t < TPW; ++t)
                acc[t * NEXP + e] += dot4(xv[t], gv);
        }
#pragma unroll
        for (int t = 0; t < TPW; ++t) xv[t] = xn[t];
    }

    // Cross-lane reduce: 16 values over 64 lanes (bits 0-3), then fold 16/32.
    reduce_stage<8>(acc, lane);
    reduce_stage<4>(acc, lane);
    reduce_stage<2>(acc, lane);
    reduce_stage<1>(acc, lane);
    float v = acc[0];
    v += __shfl_xor(v, 16, 64);
    v += __shfl_xor(v, 32, 64);
    // Lane l holds the full logit for token t_base + ((l>>3)&1), expert l&7.
    const float logit = v;

    // Gather this token-group's 8 logits (source lane shares bit 3 = token bit).
    const int base = lane & 56;
    float lg[NEXP];
#pragma unroll
    for (int e = 0; e < NEXP; ++e) lg[e] = __shfl(logit, base + e, 64);

    // top-2, lowest index wins ties (matches jax.lax.top_k)
    int i1 = 0; float m1 = lg[0];
#pragma unroll
    for (int e = 1; e < NEXP; ++e) {
        if (lg[e] > m1) { m1 = lg[e]; i1 = e; }
    }
    int i2 = 1; float m2 = -3.4e38f;
#pragma unroll
    for (int e = 0; e < NEXP; ++e) {
        if (e != i1 && lg[e] > m2) { m2 = lg[e]; i2 = e; }
    }

    // Renormalized softmax over the top-2 (other experts cancel exactly).
    const float r  = __expf(m2 - m1);  // <= 1
    const float w1 = 1.f / (1.f + r);
    const float w2 = 1.f - w1;

    const bool leader = ((lane & 7) == 0) && (lane < 16);  // lanes 0 and 8
    const int  tok    = t_base + (lane >> 3);
    if (leader) {
        out[tok * 2 + 0] = w1;
        out[tok * 2 + 1] = w2;
        out[2 * T_TOKENS + tok * 2 + 0] = (float)i1;  // indices as f32 (flat f32 out)
        out[2 * T_TOKENS + tok * 2 + 1] = (float)i2;
        // Per-token expert counts into the block-level LDS histogram.
        atomicAdd(&hist[i1], 1);
        atomicAdd(&hist[i2], 1);
    }
    __syncthreads();

    // One thread per block: push histogram, then last-arriving block computes
    // the aux loss (device-scope atomics -> coherent across XCDs).
    if (tid == 0) {
#pragma unroll
        for (int e = 0; e < NEXP; ++e) atomicAdd(&gcnt[e], hist[e]);
        __threadfence();  // counts globally visible before the flag bump
        int old = atomicAdd(flag, 1);
        if (old == NBLOCKS - 1) {
            float m[NEXP];
            float s = 0.f;
#pragma unroll
            for (int e = 0; e < NEXP; ++e) {
                int c = atomicAdd(&gcnt[e], 0);  // atomic RMW read: XCD-coherent
                m[e] = (float)c / (float)T_TOKENS;
                s += m[e];
            }
            const float mean = s / (float)NEXP;
            float var = 0.f;
#pragma unroll
            for (int e = 0; e < NEXP; ++e) {
                float d = m[e] - mean;
                var += d * d;
            }
            var /= (float)(NEXP - 1);        // unbiased (ddof=1), matches torch.var
            out[4 * T_TOKENS] = var * (float)NEXP;
        }
    }
}

extern "C" void kernel_launch(void* const* d_in, const int* in_sizes, int n_in,
                              void* d_out, int out_size, void* d_ws, size_t ws_size,
                              hipStream_t stream) {
    const float* x  = (const float*)d_in[0];
    const float* gw = (const float*)d_in[1];
    float* out = (float*)d_out;
    int* gcnt  = (int*)d_ws;
    int* flag  = gcnt + NEXP;

    hipMemsetAsync(d_ws, 0, 16 * sizeof(int), stream);  // gcnt[8] + flag
    router_fused<<<NBLOCKS, 256, 0, stream>>>(x, gw, out, gcnt, flag);
}

// Round 5
// 279.615 us; speedup vs baseline: 1.4042x; 1.4042x over previous
//
#include <hip/hip_runtime.h>
#include <stdint.h>

// Problem constants (fixed by the reference)
#define T_TOKENS 16384   // B*S = 4*4096
#define HDIM     2048
#define NEXP     8
#define NCHUNK   (HDIM / 256)                    // 8 chunks of 256 floats
#define TPW      2                               // tokens per wave
#define WPB      8                               // waves per block (512 threads)
#define TOK_PER_BLOCK (WPB * TPW)                // 16
#define NBLOCKS  (T_TOKENS / TOK_PER_BLOCK)      // 1024

typedef const __attribute__((address_space(1))) uint32_t* gas_ptr;
typedef __attribute__((address_space(3))) uint32_t*       las_ptr;

__device__ __forceinline__ float dot4(float4 a, float4 b) {
    return a.x * b.x + a.y * b.y + a.z * b.z + a.w * b.w;
}

// Value-splitting butterfly stage: 2*D live accumulators -> D.
template <int D>
__device__ __forceinline__ void reduce_stage(float (&acc)[TPW * NEXP], int lane) {
    const bool upper = (lane & D) != 0;
#pragma unroll
    for (int i = 0; i < D; ++i) {
        float send = upper ? acc[i] : acc[i + D];
        float recv = __shfl_xor(send, D, 64);
        float keep = upper ? acc[i + D] : acc[i];
        acc[i] = keep + recv;
    }
}

// Rounds 2+3 post-mortem: tight VGPR caps (64, then ~85) made the allocator
// spill acc[] to scratch (WRITE_SIZE 159MB / 48.6MB vs 0.3MB legit; VALUBusy
// 4-8%). This round: cap 128 via (512,4); gate staged via global_load_lds
// (direct DMA, ZERO staging VGPRs); the wave's whole x footprint (16 float4 =
// 64 VGPR) deliberately preloaded. Planned live ~95 < 128 -> no forced spill.
// Occupancy: 64KB LDS / 512 thr -> 2 blocks/CU = 16 waves/CU (50%).
__global__ __launch_bounds__(512, 4) void router_fused(
    const float* __restrict__ x, const float* __restrict__ gate_w,
    float* __restrict__ out, int* __restrict__ gcnt, int* __restrict__ flag) {
    __shared__ float lds_gate[NEXP * HDIM];  // 65536 bytes
    __shared__ int   hist[NEXP];

    const int tid  = threadIdx.x;
    const int lane = tid & 63;
    const int wave = tid >> 6;
    if (tid < NEXP) hist[tid] = 0;

    // Stage gate_w (8x2048 f32 = 64 KB) via async global->LDS DMA: per wave,
    // 8 issues x 1 KB. LDS dest is wave-uniform base (+ lane*16B by HW);
    // global src is per-lane. No register round-trip for gate data.
    const float4* g4 = (const float4*)gate_w;
    float4* l4 = (float4*)lds_gate;
#pragma unroll
    for (int i = 0; i < (NEXP * HDIM / 4) / 512; ++i) {
        __builtin_amdgcn_global_load_lds(
            (gas_ptr)(g4 + i * 512 + wave * 64 + lane),
            (las_ptr)(l4 + i * 512 + wave * 64), 16, 0, 0);
    }

    const int t_base = (blockIdx.x * WPB + wave) * TPW;  // exact cover of T_TOKENS

    // Issue ALL x loads for this wave's 2 tokens up-front: 16 global_load_dwordx4
    // in flight per lane (16 KB/wave) -- one HBM latency exposure, max MLP.
    const float4* x4 = (const float4*)x;
    const int row = HDIM / 4;  // 512 float4 per token
    float4 xv[TPW][NCHUNK];
#pragma unroll
    for (int t = 0; t < TPW; ++t)
#pragma unroll
        for (int c = 0; c < NCHUNK; ++c)
            xv[t][c] = x4[(size_t)(t_base + t) * row + c * 64 + lane];

    float acc[TPW * NEXP];
#pragma unroll
    for (int v = 0; v < TPW * NEXP; ++v) acc[v] = 0.f;

    __syncthreads();  // drains vmcnt(0): gate DMA complete (also covers hist init)

    // Pure LDS + FMA block; all indices compile-time (full unroll).
#pragma unroll
    for (int c = 0; c < NCHUNK; ++c) {
#pragma unroll
        for (int e = 0; e < NEXP; ++e) {
            float4 gv = l4[e * row + c * 64 + lane];
#pragma unroll
            for (int t = 0; t < TPW; ++t)
                acc[t * NEXP + e] += dot4(xv[t][c], gv);
        }
    }

    // Cross-lane reduce: 16 values over 64 lanes (bits 0-3), then fold 16/32.
    reduce_stage<8>(acc, lane);
    reduce_stage<4>(acc, lane);
    reduce_stage<2>(acc, lane);
    reduce_stage<1>(acc, lane);
    float v = acc[0];
    v += __shfl_xor(v, 16, 64);
    v += __shfl_xor(v, 32, 64);
    // Lane l holds the full logit for token t_base + ((l>>3)&1), expert l&7.
    const float logit = v;

    // Gather this token-group's 8 logits (source lane shares bit 3 = token bit).
    const int base = lane & 56;
    float lg[NEXP];
#pragma unroll
    for (int e = 0; e < NEXP; ++e) lg[e] = __shfl(logit, base + e, 64);

    // top-2, lowest index wins ties (matches jax.lax.top_k)
    int i1 = 0; float m1 = lg[0];
#pragma unroll
    for (int e = 1; e < NEXP; ++e) {
        if (lg[e] > m1) { m1 = lg[e]; i1 = e; }
    }
    int i2 = 1; float m2 = -3.4e38f;
#pragma unroll
    for (int e = 0; e < NEXP; ++e) {
        if (e != i1 && lg[e] > m2) { m2 = lg[e]; i2 = e; }
    }

    // Renormalized softmax over the top-2 (other experts cancel exactly).
    const float r  = __expf(m2 - m1);  // <= 1
    const float w1 = 1.f / (1.f + r);
    const float w2 = 1.f - w1;

    const bool leader = ((lane & 7) == 0) && (lane < 16);  // lanes 0 and 8
    const int  tok    = t_base + (lane >> 3);
    if (leader) {
        out[tok * 2 + 0] = w1;
        out[tok * 2 + 1] = w2;
        out[2 * T_TOKENS + tok * 2 + 0] = (float)i1;  // indices as f32 (flat f32 out)
        out[2 * T_TOKENS + tok * 2 + 1] = (float)i2;
        // Per-token expert counts into the block-level LDS histogram.
        atomicAdd(&hist[i1], 1);
        atomicAdd(&hist[i2], 1);
    }
    __syncthreads();

    // One thread per block: push histogram, then last-arriving block computes
    // the aux loss (device-scope atomics -> coherent across XCDs).
    if (tid == 0) {
#pragma unroll
        for (int e = 0; e < NEXP; ++e) atomicAdd(&gcnt[e], hist[e]);
        __threadfence();  // counts globally visible before the flag bump
        int old = atomicAdd(flag, 1);
        if (old == NBLOCKS - 1) {
            float m[NEXP];
            float s = 0.f;
#pragma unroll
            for (int e = 0; e < NEXP; ++e) {
                int c = atomicAdd(&gcnt[e], 0);  // atomic RMW read: XCD-coherent
                m[e] = (float)c / (float)T_TOKENS;
                s += m[e];
            }
            const float mean = s / (float)NEXP;
            float var = 0.f;
#pragma unroll
            for (int e = 0; e < NEXP; ++e) {
                float d = m[e] - mean;
                var += d * d;
            }
            var /= (float)(NEXP - 1);        // unbiased (ddof=1), matches torch.var
            out[4 * T_TOKENS] = var * (float)NEXP;
        }
    }
}

extern "C" void kernel_launch(void* const* d_in, const int* in_sizes, int n_in,
                              void* d_out, int out_size, void* d_ws, size_t ws_size,
                              hipStream_t stream) {
    const float* x  = (const float*)d_in[0];
    const float* gw = (const float*)d_in[1];
    float* out = (float*)d_out;
    int* gcnt  = (int*)d_ws;
    int* flag  = gcnt + NEXP;

    hipMemsetAsync(d_ws, 0, 16 * sizeof(int), stream);  // gcnt[8] + flag
    router_fused<<<NBLOCKS, 512, 0, stream>>>(x, gw, out, gcnt, flag);
}

// Round 6
// 192.577 us; speedup vs baseline: 2.0389x; 1.4520x over previous
//
#include <hip/hip_runtime.h>
#include <stdint.h>

// Problem constants (fixed by the reference)
#define T_TOKENS 16384   // B*S = 4*4096
#define HDIM     2048
#define NEXP     8
#define NCHUNK   (HDIM / 256)                    // 8 chunks of 256 floats
#define TPW      2                               // tokens per wave
#define WPB      8                               // waves per block (512 threads)
#define TOK_PER_BLOCK (WPB * TPW)                // 16
#define NBLOCKS  (T_TOKENS / TOK_PER_BLOCK)      // 1024

typedef const __attribute__((address_space(1))) uint32_t* gas_ptr;
typedef __attribute__((address_space(3))) uint32_t*       las_ptr;

__device__ __forceinline__ float dot4(float4 a, float4 b) {
    return a.x * b.x + a.y * b.y + a.z * b.z + a.w * b.w;
}

// Value-splitting butterfly stage: 2*D live accumulators -> D.
template <int D>
__device__ __forceinline__ void reduce_stage(float (&acc)[TPW * NEXP], int lane) {
    const bool upper = (lane & D) != 0;
#pragma unroll
    for (int i = 0; i < D; ++i) {
        float send = upper ? acc[i] : acc[i + D];
        float recv = __shfl_xor(send, D, 64);
        float keep = upper ? acc[i + D] : acc[i];
        acc[i] = keep + recv;
    }
}

// Round-5 post-mortem: spill eliminated (WRITE 48.6MB->0.57MB) but duration
// memory-invariant at 143us (FETCH~0 dispatch = same time). New theory: the
// per-block device-scope atomic finale (8 same-line gcnt adds + threadfence +
// returning flag RMW on ONE hot address) serializes ~9K RMWs at the coherence
// point across 8 XCDs; dur scaled with block count (210/252/143us at
// 65K/20K/9K ops), and occupancy 22% = waves parked on the fence+flag.
// Fix: ZERO global atomics here -- per-block histogram to a private workspace
// slot via plain stores; tiny second kernel reduces 1024x8 ints + aux loss.
__global__ __launch_bounds__(512, 4) void router_fused(
    const float* __restrict__ x, const float* __restrict__ gate_w,
    float* __restrict__ out, int* __restrict__ gpart) {
    __shared__ float lds_gate[NEXP * HDIM];  // 65536 bytes
    __shared__ int   hist[NEXP];

    const int tid  = threadIdx.x;
    const int lane = tid & 63;
    const int wave = tid >> 6;
    if (tid < NEXP) hist[tid] = 0;

    // Stage gate_w (8x2048 f32 = 64 KB) via async global->LDS DMA: per wave,
    // 8 issues x 1 KB. Zero VGPR round-trip for gate data (round-5 verified).
    const float4* g4 = (const float4*)gate_w;
    float4* l4 = (float4*)lds_gate;
#pragma unroll
    for (int i = 0; i < (NEXP * HDIM / 4) / 512; ++i) {
        __builtin_amdgcn_global_load_lds(
            (gas_ptr)(g4 + i * 512 + wave * 64 + lane),
            (las_ptr)(l4 + i * 512 + wave * 64), 16, 0, 0);
    }

    const int t_base = (blockIdx.x * WPB + wave) * TPW;  // exact cover of T_TOKENS

    // Issue ALL x loads for this wave's 2 tokens up-front (16 dwordx4 in flight).
    const float4* x4 = (const float4*)x;
    const int row = HDIM / 4;  // 512 float4 per token
    float4 xv[TPW][NCHUNK];
#pragma unroll
    for (int t = 0; t < TPW; ++t)
#pragma unroll
        for (int c = 0; c < NCHUNK; ++c)
            xv[t][c] = x4[(size_t)(t_base + t) * row + c * 64 + lane];

    float acc[TPW * NEXP];
#pragma unroll
    for (int v = 0; v < TPW * NEXP; ++v) acc[v] = 0.f;

    __syncthreads();  // drains vmcnt(0): gate DMA + x loads complete; hist init

    // Pure LDS + FMA block; all indices compile-time (full unroll).
#pragma unroll
    for (int c = 0; c < NCHUNK; ++c) {
#pragma unroll
        for (int e = 0; e < NEXP; ++e) {
            float4 gv = l4[e * row + c * 64 + lane];
#pragma unroll
            for (int t = 0; t < TPW; ++t)
                acc[t * NEXP + e] += dot4(xv[t][c], gv);
        }
    }

    // Cross-lane reduce: 16 values over 64 lanes (bits 0-3), then fold 16/32.
    reduce_stage<8>(acc, lane);
    reduce_stage<4>(acc, lane);
    reduce_stage<2>(acc, lane);
    reduce_stage<1>(acc, lane);
    float v = acc[0];
    v += __shfl_xor(v, 16, 64);
    v += __shfl_xor(v, 32, 64);
    // Lane l holds the full logit for token t_base + ((l>>3)&1), expert l&7.
    const float logit = v;

    // Gather this token-group's 8 logits (source lane shares bit 3 = token bit).
    const int base = lane & 56;
    float lg[NEXP];
#pragma unroll
    for (int e = 0; e < NEXP; ++e) lg[e] = __shfl(logit, base + e, 64);

    // top-2, lowest index wins ties (matches jax.lax.top_k)
    int i1 = 0; float m1 = lg[0];
#pragma unroll
    for (int e = 1; e < NEXP; ++e) {
        if (lg[e] > m1) { m1 = lg[e]; i1 = e; }
    }
    int i2 = 1; float m2 = -3.4e38f;
#pragma unroll
    for (int e = 0; e < NEXP; ++e) {
        if (e != i1 && lg[e] > m2) { m2 = lg[e]; i2 = e; }
    }

    // Renormalized softmax over the top-2 (other experts cancel exactly).
    const float r  = __expf(m2 - m1);  // <= 1
    const float w1 = 1.f / (1.f + r);
    const float w2 = 1.f - w1;

    const bool leader = ((lane & 7) == 0) && (lane < 16);  // lanes 0 and 8
    const int  tok    = t_base + (lane >> 3);
    if (leader) {
        out[tok * 2 + 0] = w1;
        out[tok * 2 + 1] = w2;
        out[2 * T_TOKENS + tok * 2 + 0] = (float)i1;  // indices as f32 (flat f32 out)
        out[2 * T_TOKENS + tok * 2 + 1] = (float)i2;
        // Per-token expert counts into the block-level LDS histogram (16 LDS
        // atomics per block -- trivial).
        atomicAdd(&hist[i1], 1);
        atomicAdd(&hist[i2], 1);
    }
    __syncthreads();

    // Plain stores to this block's private slot. No atomics, no fence, no flag.
    if (tid < NEXP) gpart[blockIdx.x * NEXP + tid] = hist[tid];
}

// Reduce the 1024x8 partial-histogram table and compute the aux loss.
// Kernel boundary provides the global visibility ordering.
__global__ void router_aux(const int* __restrict__ gpart, float* __restrict__ out) {
    __shared__ int part[256];
    const int t = threadIdx.x;
    int s = 0;
#pragma unroll
    for (int i = 0; i < (NBLOCKS * NEXP) / 256; ++i)  // 32 iters, coalesced
        s += gpart[i * 256 + t];
    part[t] = s;  // thread t's sum is purely expert t&7 (256 % 8 == 0)
    __syncthreads();
    if (t < NEXP) {
        int c = 0;
#pragma unroll
        for (int i = 0; i < 256 / NEXP; ++i) c += part[t + i * NEXP];
        part[t] = c;  // per-expert total
    }
    __syncthreads();
    if (t == 0) {
        float m[NEXP];
        float ssum = 0.f;
#pragma unroll
        for (int e = 0; e < NEXP; ++e) {
            m[e] = (float)part[e] / (float)T_TOKENS;
            ssum += m[e];
        }
        const float mean = ssum / (float)NEXP;
        float var = 0.f;
#pragma unroll
        for (int e = 0; e < NEXP; ++e) {
            float d = m[e] - mean;
            var += d * d;
        }
        var /= (float)(NEXP - 1);            // unbiased (ddof=1), matches torch.var
        out[4 * T_TOKENS] = var * (float)NEXP;
    }
}

extern "C" void kernel_launch(void* const* d_in, const int* in_sizes, int n_in,
                              void* d_out, int out_size, void* d_ws, size_t ws_size,
                              hipStream_t stream) {
    const float* x  = (const float*)d_in[0];
    const float* gw = (const float*)d_in[1];
    float* out = (float*)d_out;
    int* gpart = (int*)d_ws;  // NBLOCKS*NEXP ints = 32 KB; every slot written,
                              // so no memset dispatch needed.

    router_fused<<<NBLOCKS, 512, 0, stream>>>(x, gw, out, gpart);
    router_aux<<<1, 256, 0, stream>>>(gpart, out);
}